// Round 4
// baseline (3955.827 us; speedup 1.0000x reference)
//
#include <hip/hip_runtime.h>
#include <math.h>

// Problem constants (match reference)
#define NB   8192
#define DD   64
#define OO   32
#define KK   15
#define HID  60

#define LDF  68      // row stride (words) for 64-wide LDS tiles
#define LDT  72      // row stride for FP scratch tile
#define SST  36      // row stride for 32x32 matrices
#define XOFF (32*LDF)  // X = L^{-1} HP lives in sT after HP rows

#define LOG2PI 1.8378770664093453f

typedef float f32x4 __attribute__((ext_vector_type(4)));  // for nontemporal builtins

__global__ __launch_bounds__(512, 4)
void rkn_kernel(const float* __restrict__ state_mean,
                const float* __restrict__ state_cov,
                const float* __restrict__ obs,
                const float* __restrict__ w1,
                const float* __restrict__ b1,
                const float* __restrict__ w2,
                const float* __restrict__ b2,
                const float* __restrict__ basis,
                const float* __restrict__ pnf,
                const float* __restrict__ pnd,
                const float* __restrict__ onf,
                const float* __restrict__ ond,
                const float* __restrict__ Hw,
                const float* __restrict__ Hb,
                float* __restrict__ out_pm,
                float* __restrict__ out_pc,
                float* __restrict__ out_ll)
{
  __shared__ __align__(16) float sF [64*LDF];   // F
  __shared__ __align__(16) float sP [64*LDF];   // state_cov -> pred_cov
  __shared__ __align__(16) float sT [64*LDT];   // FP ; then HP rows [0,2176) + X [2176,4352)
  __shared__ __align__(16) float sHw[32*LDF];   // Hw staged
  __shared__ __align__(16) float sS [32*SST];   // S -> L
  __shared__ __align__(16) float sm_[64];
  __shared__ __align__(16) float pm_[64];
  __shared__ __align__(16) float h_ [64];
  __shared__ __align__(16) float inn_[32];
  __shared__ __align__(16) float y_ [32];
  __shared__ float wts_[16];
  __shared__ float redA[32];    // log(diag L)
  __shared__ float rdiag_[32];  // 1/diag(L)
  __shared__ float qd_;         // quad = y.y
  __shared__ __align__(16) float spnf[64*4];
  __shared__ float spd[64];
  __shared__ __align__(16) float sonf[32*4];
  __shared__ float sod[32];

  const int t = threadIdx.x;
  const int b = blockIdx.x;

  // ---------------- stage globals ----------------
  {
    const float4* cov4 = (const float4*)(state_cov + (size_t)b * 4096);
    #pragma unroll
    for (int r = 0; r < 2; r++) {
      int idx = t + 512*r;
      int row = idx >> 4, c4 = idx & 15;
      *(float4*)&sP[row*LDF + c4*4] = cov4[idx];
    }
    const float4* hw4 = (const float4*)Hw;
    {
      int row = t >> 4, c4 = t & 15;
      *(float4*)&sHw[row*LDF + c4*4] = hw4[t];
    }
    if (t < 64) {
      sm_[t] = state_mean[(size_t)b*64 + t];
      spnf[t*4+0] = pnf[t*3+0];
      spnf[t*4+1] = pnf[t*3+1];
      spnf[t*4+2] = pnf[t*3+2];
      spnf[t*4+3] = 0.0f;
      spd[t] = expf(pnd[t]);
    }
    if (t < 32) {
      sonf[t*4+0] = onf[t*3+0];
      sonf[t*4+1] = onf[t*3+1];
      sonf[t*4+2] = onf[t*3+2];
      sonf[t*4+3] = 0.0f;
      sod[t] = expf(ond[t]);
    }
  }
  __syncthreads();

  // ---------------- MLP: h = elu(W1 @ sm + b1) ----------------
  if (t < HID) {
    const float4* w1r = (const float4*)(w1 + t*64);
    float acc = 0.0f;
    #pragma unroll
    for (int m = 0; m < 16; m++) {
      float4 wv = w1r[m];
      float4 sv = *(const float4*)&sm_[4*m];
      acc += wv.x*sv.x + wv.y*sv.y + wv.z*sv.z + wv.w*sv.w;
    }
    acc += b1[t];
    h_[t] = (acc > 0.0f) ? acc : expm1f(acc);
  }
  __syncthreads();

  // logits = W2 @ h + b2
  if (t < KK) {
    const float* w2r = w2 + t*60;
    float acc = 0.0f;
    for (int m = 0; m < 60; m++) acc += w2r[m]*h_[m];
    wts_[t] = acc + b2[t];
  }
  __syncthreads();

  // softmax over 15 (serial, tiny)
  if (t == 0) {
    float mx = wts_[0];
    for (int k = 1; k < KK; k++) mx = fmaxf(mx, wts_[k]);
    float s = 0.0f;
    for (int k = 0; k < KK; k++) { float e = expf(wts_[k]-mx); wts_[k] = e; s += e; }
    float inv = 1.0f/s;
    for (int k = 0; k < KK; k++) wts_[k] *= inv;
  }
  __syncthreads();

  // ---------------- F = sum_k w_k * basis_k ----------------
  {
    float w[KK];
    #pragma unroll
    for (int k = 0; k < KK; k++) w[k] = wts_[k];
    const float4* bas4 = (const float4*)basis;
    #pragma unroll
    for (int r = 0; r < 2; r++) {
      int idx = t + 512*r;
      float4 acc; acc.x = 0; acc.y = 0; acc.z = 0; acc.w = 0;
      #pragma unroll
      for (int k = 0; k < KK; k++) {
        float4 bv = bas4[k*1024 + idx];
        acc.x += w[k]*bv.x; acc.y += w[k]*bv.y;
        acc.z += w[k]*bv.z; acc.w += w[k]*bv.w;
      }
      int row = idx >> 4, c4 = idx & 15;
      *(float4*)&sF[row*LDF + c4*4] = acc;
    }
  }
  __syncthreads();

  const int tr = t >> 4, tc = t & 15;   // 32 x 16 thread grid
  const int i0 = tr*2, j0 = tc*4;       // 2x4 output tile

  // ---------------- FP = F @ P  -> sT ; pred_mean = F @ sm ----------------
  {
    float acc[2][4] = {};
    for (int k = 0; k < 64; k += 4) {
      float4 a0 = *(const float4*)&sF[(i0  )*LDF + k];
      float4 a1 = *(const float4*)&sF[(i0+1)*LDF + k];
      float4 bb[4];
      #pragma unroll
      for (int kk = 0; kk < 4; kk++) bb[kk] = *(const float4*)&sP[(k+kk)*LDF + j0];
      const float* b0 = (const float*)&bb[0]; const float* b1p = (const float*)&bb[1];
      const float* b2p = (const float*)&bb[2]; const float* b3 = (const float*)&bb[3];
      #pragma unroll
      for (int c = 0; c < 4; c++) {
        acc[0][c] += a0.x*b0[c] + a0.y*b1p[c] + a0.z*b2p[c] + a0.w*b3[c];
        acc[1][c] += a1.x*b0[c] + a1.y*b1p[c] + a1.z*b2p[c] + a1.w*b3[c];
      }
    }
    #pragma unroll
    for (int r = 0; r < 2; r++) {
      float4 st; st.x = acc[r][0]; st.y = acc[r][1]; st.z = acc[r][2]; st.w = acc[r][3];
      *(float4*)&sT[(i0+r)*LDT + j0] = st;
    }
  }
  if (t < 64) {
    float acc = 0.0f;
    #pragma unroll
    for (int m = 0; m < 16; m++) {
      float4 fv = *(const float4*)&sF[t*LDF + 4*m];
      float4 sv = *(const float4*)&sm_[4*m];
      acc += fv.x*sv.x + fv.y*sv.y + fv.z*sv.z + fv.w*sv.w;
    }
    pm_[t] = acc;
  }
  __syncthreads();

  // ---------------- pred_cov = FP @ F^T + Q -> sP ; innovation ----------------
  {
    float acc[2][4] = {};
    for (int k = 0; k < 64; k += 4) {
      float4 a0 = *(const float4*)&sT[(i0  )*LDT + k];
      float4 a1 = *(const float4*)&sT[(i0+1)*LDT + k];
      #pragma unroll
      for (int c = 0; c < 4; c++) {
        float4 bv = *(const float4*)&sF[(j0+c)*LDF + k];
        acc[0][c] += a0.x*bv.x + a0.y*bv.y + a0.z*bv.z + a0.w*bv.w;
        acc[1][c] += a1.x*bv.x + a1.y*bv.y + a1.z*bv.z + a1.w*bv.w;
      }
    }
    #pragma unroll
    for (int r = 0; r < 2; r++) {
      int i = i0 + r;
      float4 st;
      float* pst = (float*)&st;
      #pragma unroll
      for (int c = 0; c < 4; c++) {
        int j = j0 + c;
        float q = spnf[i*4+0]*spnf[j*4+0] + spnf[i*4+1]*spnf[j*4+1] + spnf[i*4+2]*spnf[j*4+2];
        if (i == j) q += spd[i];
        pst[c] = acc[r][c] + q;
      }
      *(float4*)&sP[i*LDF + j0] = st;
    }
  }
  if (t < 32) {
    float acc = 0.0f;
    #pragma unroll
    for (int m = 0; m < 16; m++) {
      float4 hv = *(const float4*)&sHw[t*LDF + 4*m];
      float4 pv = *(const float4*)&pm_[4*m];
      acc += hv.x*pv.x + hv.y*pv.y + hv.z*pv.z + hv.w*pv.w;
    }
    inn_[t] = obs[(size_t)b*32 + t] - (acc + Hb[t]);
  }
  __syncthreads();

  // ---------------- HP = Hw @ pred_cov -> sT rows [0,32) (overwrites FP) ----------------
  {
    const int hr = t >> 4, hc0 = (t & 15)*4;   // 1x4 tile, 32x16 grid
    float acc[4] = {};
    for (int k = 0; k < 64; k += 4) {
      float4 a = *(const float4*)&sHw[hr*LDF + k];
      float4 bb[4];
      #pragma unroll
      for (int kk = 0; kk < 4; kk++) bb[kk] = *(const float4*)&sP[(k+kk)*LDF + hc0];
      const float* b0 = (const float*)&bb[0]; const float* b1p = (const float*)&bb[1];
      const float* b2p = (const float*)&bb[2]; const float* b3 = (const float*)&bb[3];
      #pragma unroll
      for (int c = 0; c < 4; c++)
        acc[c] += a.x*b0[c] + a.y*b1p[c] + a.z*b2p[c] + a.w*b3[c];
    }
    float4 s0; s0.x = acc[0]; s0.y = acc[1]; s0.z = acc[2]; s0.w = acc[3];
    *(float4*)&sT[hr*LDF + hc0] = s0;
  }
  __syncthreads();

  // ---------------- S = HP @ Hw^T + Rn -> sS ----------------
  if (t < 256) {
    const int so = t >> 3, sp0 = (t & 7)*4;
    float acc[4] = {};
    for (int k = 0; k < 64; k += 4) {
      float4 av = *(const float4*)&sT[so*LDF + k];
      #pragma unroll
      for (int c = 0; c < 4; c++) {
        float4 bv = *(const float4*)&sHw[(sp0+c)*LDF + k];
        acc[c] += av.x*bv.x + av.y*bv.y + av.z*bv.z + av.w*bv.w;
      }
    }
    #pragma unroll
    for (int c = 0; c < 4; c++) {
      int p = sp0 + c;
      float rn = sonf[so*4+0]*sonf[p*4+0] + sonf[so*4+1]*sonf[p*4+1] + sonf[so*4+2]*sonf[p*4+2];
      if (so == p) rn += sod[so];
      sS[so*SST + p] = acc[c] + rn;
    }
  }
  __syncthreads();

  // ---------------- Cholesky: wave 0, in-register, shfl broadcasts, NO barriers ----------
  if (t < 64) {
    const int lane = t;
    const int li = (lane < 32) ? lane : 0;
    float r[32];
    #pragma unroll
    for (int j = 0; j < 32; j++) r[j] = sS[li*SST + j];
    float my_sd = 1.0f;
    #pragma unroll
    for (int k = 0; k < 32; k++) {
      float dk = __shfl(r[k], k);
      float sd = sqrtf(dk);
      float lik = r[k] * (1.0f/sd);
      if (lane == k) my_sd = sd;
      r[k] = lik;
      #pragma unroll
      for (int j = k+1; j < 32; j++) {
        float ljk = __shfl(lik, j);
        if (lane >= j) r[j] -= lik * ljk;
      }
    }
    if (lane < 32) {
      #pragma unroll
      for (int j = 0; j < 32; j++) sS[lane*SST + j] = r[j];  // junk above diag, never read
      rdiag_[lane] = 1.0f / my_sd;
      redA[lane]   = logf(my_sd);
    }
  }
  __syncthreads();

  // ---------------- X = L^{-1} HP (wave 0: 64 cols) ; y = L^{-1} inn (wave 1) ----------
  if (t < 128) {
    float x[32];
    if (t < 64) {
      #pragma unroll
      for (int i = 0; i < 32; i++) x[i] = sT[i*LDF + t];
    } else {
      #pragma unroll
      for (int i = 0; i < 32; i++) x[i] = inn_[i];
    }
    #pragma unroll
    for (int m = 0; m < 32; m++) {
      x[m] *= rdiag_[m];
      #pragma unroll
      for (int i = m+1; i < 32; i++) x[i] -= sS[i*SST + m] * x[m];
    }
    if (t < 64) {
      #pragma unroll
      for (int i = 0; i < 32; i++) sT[XOFF + i*LDF + t] = x[i];
    } else if (t == 64) {
      float q = 0.0f;
      #pragma unroll
      for (int i = 0; i < 32; i++) { y_[i] = x[i]; q += x[i]*x[i]; }
      qd_ = q;
    }
  }
  __syncthreads();

  // ---------------- post_cov = pred_cov - X^T X -> global (non-temporal) ----------------
  {
    float acc[2][4] = {};
    for (int o = 0; o < 32; o++) {
      float2 xa = *(const float2*)&sT[XOFF + o*LDF + i0];
      float4 xb = *(const float4*)&sT[XOFF + o*LDF + j0];
      const float* bp = (const float*)&xb;
      #pragma unroll
      for (int c = 0; c < 4; c++) {
        acc[0][c] += xa.x * bp[c];
        acc[1][c] += xa.y * bp[c];
      }
    }
    #pragma unroll
    for (int r = 0; r < 2; r++) {
      int i = i0 + r;
      f32x4 st;
      st.x = sP[i*LDF + j0+0] - acc[r][0];
      st.y = sP[i*LDF + j0+1] - acc[r][1];
      st.z = sP[i*LDF + j0+2] - acc[r][2];
      st.w = sP[i*LDF + j0+3] - acc[r][3];
      __builtin_nontemporal_store(st, (f32x4*)&out_pc[(size_t)b*4096 + i*64 + j0]);
    }
  }
  // post_mean = pred_mean + X^T y
  if (t < 64) {
    float acc = pm_[t];
    #pragma unroll
    for (int i = 0; i < 32; i++) acc += sT[XOFF + i*LDF + t] * y_[i];
    __builtin_nontemporal_store(acc, &out_pm[(size_t)b*64 + t]);
  }
  // log-likelihood
  if (t == 0) {
    float ld = 0.0f;
    for (int k = 0; k < 32; k++) ld += redA[k];
    out_ll[b] = -0.5f*(2.0f*ld + qd_ + 32.0f*LOG2PI);
  }
}

extern "C" void kernel_launch(void* const* d_in, const int* in_sizes, int n_in,
                              void* d_out, int out_size, void* d_ws, size_t ws_size,
                              hipStream_t stream) {
  const float* state_mean = (const float*)d_in[0];
  const float* state_cov  = (const float*)d_in[1];
  const float* obs        = (const float*)d_in[2];
  const float* w1         = (const float*)d_in[3];
  const float* b1         = (const float*)d_in[4];
  const float* w2         = (const float*)d_in[5];
  const float* b2         = (const float*)d_in[6];
  const float* basis      = (const float*)d_in[7];
  const float* pnf        = (const float*)d_in[8];
  const float* pnd        = (const float*)d_in[9];
  const float* onf        = (const float*)d_in[10];
  const float* ond        = (const float*)d_in[11];
  const float* Hw         = (const float*)d_in[12];
  const float* Hb         = (const float*)d_in[13];

  const int Bn = in_sizes[0] / 64;
  float* out = (float*)d_out;
  float* out_pm = out;
  float* out_pc = out + (size_t)Bn*64;
  float* out_ll = out + (size_t)Bn*64 + (size_t)Bn*4096;

  hipLaunchKernelGGL(rkn_kernel, dim3(Bn), dim3(512), 0, stream,
                     state_mean, state_cov, obs, w1, b1, w2, b2, basis,
                     pnf, pnd, onf, ond, Hw, Hb, out_pm, out_pc, out_ll);
}

// Round 5
// 3789.257 us; speedup vs baseline: 1.0440x; 1.0440x over previous
//
#include <hip/hip_runtime.h>
#include <math.h>

// Problem constants (match reference)
#define NB   8192
#define DD   64
#define OO   32
#define KK   15
#define HID  60

#define LDF  68      // row stride (words) for 64-wide LDS tiles
#define LDT  72      // row stride for FP scratch tile
#define SST  36      // row stride for 32x32 matrices
#define XOFF (32*LDF)  // X = L^{-1} HP lives in sT after HP rows

#define LOG2PI 1.8378770664093453f

// clang ext vectors: stay in registers, support [] with constant index,
// scalar broadcast arithmetic, and nontemporal builtins. NEVER take their address.
typedef float f32x4 __attribute__((ext_vector_type(4)));
typedef float f32x2 __attribute__((ext_vector_type(2)));

__global__ __launch_bounds__(512, 4)
void rkn_kernel(const float* __restrict__ state_mean,
                const float* __restrict__ state_cov,
                const float* __restrict__ obs,
                const float* __restrict__ w1,
                const float* __restrict__ b1,
                const float* __restrict__ w2,
                const float* __restrict__ b2,
                const float* __restrict__ basis,
                const float* __restrict__ pnf,
                const float* __restrict__ pnd,
                const float* __restrict__ onf,
                const float* __restrict__ ond,
                const float* __restrict__ Hw,
                const float* __restrict__ Hb,
                float* __restrict__ out_pm,
                float* __restrict__ out_pc,
                float* __restrict__ out_ll)
{
  __shared__ __align__(16) float sF [64*LDF];   // F
  __shared__ __align__(16) float sP [64*LDF];   // state_cov -> pred_cov
  __shared__ __align__(16) float sT [64*LDT];   // FP ; then HP rows [0,2176) + X [2176,4352)
  __shared__ __align__(16) float sHw[32*LDF];   // Hw staged
  __shared__ __align__(16) float sS [32*SST];   // S -> L
  __shared__ __align__(16) float sm_[64];
  __shared__ __align__(16) float pm_[64];
  __shared__ __align__(16) float h_ [64];
  __shared__ __align__(16) float inn_[32];
  __shared__ __align__(16) float y_ [32];
  __shared__ float wts_[16];
  __shared__ float redA[32];    // log(diag L)
  __shared__ float rdiag_[32];  // 1/diag(L)
  __shared__ float qd_;         // quad = y.y
  __shared__ __align__(16) float spnf[64*4];
  __shared__ float spd[64];
  __shared__ __align__(16) float sonf[32*4];
  __shared__ float sod[32];

  const int t = threadIdx.x;
  const int b = blockIdx.x;

  // ---------------- stage globals ----------------
  {
    const f32x4* cov4 = (const f32x4*)(state_cov + (size_t)b * 4096);
    #pragma unroll
    for (int r = 0; r < 2; r++) {
      int idx = t + 512*r;
      int row = idx >> 4, c4 = idx & 15;
      *(f32x4*)&sP[row*LDF + c4*4] = cov4[idx];
    }
    const f32x4* hw4 = (const f32x4*)Hw;
    {
      int row = t >> 4, c4 = t & 15;
      *(f32x4*)&sHw[row*LDF + c4*4] = hw4[t];
    }
    if (t < 64) {
      sm_[t] = state_mean[(size_t)b*64 + t];
      spnf[t*4+0] = pnf[t*3+0];
      spnf[t*4+1] = pnf[t*3+1];
      spnf[t*4+2] = pnf[t*3+2];
      spnf[t*4+3] = 0.0f;
      spd[t] = expf(pnd[t]);
    }
    if (t < 32) {
      sonf[t*4+0] = onf[t*3+0];
      sonf[t*4+1] = onf[t*3+1];
      sonf[t*4+2] = onf[t*3+2];
      sonf[t*4+3] = 0.0f;
      sod[t] = expf(ond[t]);
    }
  }
  __syncthreads();

  // ---------------- MLP: h = elu(W1 @ sm + b1) ----------------
  if (t < HID) {
    const f32x4* w1r = (const f32x4*)(w1 + t*64);
    float acc = 0.0f;
    #pragma unroll
    for (int m = 0; m < 16; m++) {
      f32x4 wv = w1r[m];
      f32x4 sv = *(const f32x4*)&sm_[4*m];
      acc += wv[0]*sv[0] + wv[1]*sv[1] + wv[2]*sv[2] + wv[3]*sv[3];
    }
    acc += b1[t];
    h_[t] = (acc > 0.0f) ? acc : expm1f(acc);
  }
  __syncthreads();

  // logits = W2 @ h + b2
  if (t < KK) {
    const float* w2r = w2 + t*60;
    float acc = 0.0f;
    for (int m = 0; m < 60; m++) acc += w2r[m]*h_[m];
    wts_[t] = acc + b2[t];
  }
  __syncthreads();

  // softmax over 15 (serial, tiny)
  if (t == 0) {
    float mx = wts_[0];
    for (int k = 1; k < KK; k++) mx = fmaxf(mx, wts_[k]);
    float s = 0.0f;
    for (int k = 0; k < KK; k++) { float e = expf(wts_[k]-mx); wts_[k] = e; s += e; }
    float inv = 1.0f/s;
    for (int k = 0; k < KK; k++) wts_[k] *= inv;
  }
  __syncthreads();

  // ---------------- F = sum_k w_k * basis_k ----------------
  {
    float w[KK];
    #pragma unroll
    for (int k = 0; k < KK; k++) w[k] = wts_[k];
    const f32x4* bas4 = (const f32x4*)basis;
    #pragma unroll
    for (int r = 0; r < 2; r++) {
      int idx = t + 512*r;
      f32x4 acc = {0.0f, 0.0f, 0.0f, 0.0f};
      #pragma unroll
      for (int k = 0; k < KK; k++) {
        f32x4 bv = bas4[k*1024 + idx];
        acc += w[k]*bv;
      }
      int row = idx >> 4, c4 = idx & 15;
      *(f32x4*)&sF[row*LDF + c4*4] = acc;
    }
  }
  __syncthreads();

  const int tr = t >> 4, tc = t & 15;   // 32 x 16 thread grid
  const int i0 = tr*2, j0 = tc*4;       // 2x4 output tile

  // ---------------- FP = F @ P  -> sT ; pred_mean = F @ sm ----------------
  {
    f32x4 acc0 = {0.0f,0.0f,0.0f,0.0f};
    f32x4 acc1 = {0.0f,0.0f,0.0f,0.0f};
    for (int k = 0; k < 64; k += 4) {
      f32x4 a0 = *(const f32x4*)&sF[(i0  )*LDF + k];
      f32x4 a1 = *(const f32x4*)&sF[(i0+1)*LDF + k];
      f32x4 b0 = *(const f32x4*)&sP[(k  )*LDF + j0];
      f32x4 b1v = *(const f32x4*)&sP[(k+1)*LDF + j0];
      f32x4 b2v = *(const f32x4*)&sP[(k+2)*LDF + j0];
      f32x4 b3v = *(const f32x4*)&sP[(k+3)*LDF + j0];
      acc0 += a0[0]*b0 + a0[1]*b1v + a0[2]*b2v + a0[3]*b3v;
      acc1 += a1[0]*b0 + a1[1]*b1v + a1[2]*b2v + a1[3]*b3v;
    }
    *(f32x4*)&sT[(i0  )*LDT + j0] = acc0;
    *(f32x4*)&sT[(i0+1)*LDT + j0] = acc1;
  }
  if (t < 64) {
    float acc = 0.0f;
    #pragma unroll
    for (int m = 0; m < 16; m++) {
      f32x4 fv = *(const f32x4*)&sF[t*LDF + 4*m];
      f32x4 sv = *(const f32x4*)&sm_[4*m];
      acc += fv[0]*sv[0] + fv[1]*sv[1] + fv[2]*sv[2] + fv[3]*sv[3];
    }
    pm_[t] = acc;
  }
  __syncthreads();

  // ---------------- pred_cov = FP @ F^T + Q -> sP ; innovation ----------------
  {
    f32x4 acc0 = {0.0f,0.0f,0.0f,0.0f};
    f32x4 acc1 = {0.0f,0.0f,0.0f,0.0f};
    for (int k = 0; k < 64; k += 4) {
      f32x4 a0 = *(const f32x4*)&sT[(i0  )*LDT + k];
      f32x4 a1 = *(const f32x4*)&sT[(i0+1)*LDT + k];
      #pragma unroll
      for (int c = 0; c < 4; c++) {
        f32x4 bv = *(const f32x4*)&sF[(j0+c)*LDF + k];
        acc0[c] += a0[0]*bv[0] + a0[1]*bv[1] + a0[2]*bv[2] + a0[3]*bv[3];
        acc1[c] += a1[0]*bv[0] + a1[1]*bv[1] + a1[2]*bv[2] + a1[3]*bv[3];
      }
    }
    #pragma unroll
    for (int r = 0; r < 2; r++) {
      int i = i0 + r;
      f32x4 st = (r == 0) ? acc0 : acc1;
      #pragma unroll
      for (int c = 0; c < 4; c++) {
        int j = j0 + c;
        float q = spnf[i*4+0]*spnf[j*4+0] + spnf[i*4+1]*spnf[j*4+1] + spnf[i*4+2]*spnf[j*4+2];
        if (i == j) q += spd[i];
        st[c] += q;
      }
      *(f32x4*)&sP[i*LDF + j0] = st;
    }
  }
  if (t < 32) {
    float acc = 0.0f;
    #pragma unroll
    for (int m = 0; m < 16; m++) {
      f32x4 hv = *(const f32x4*)&sHw[t*LDF + 4*m];
      f32x4 pv = *(const f32x4*)&pm_[4*m];
      acc += hv[0]*pv[0] + hv[1]*pv[1] + hv[2]*pv[2] + hv[3]*pv[3];
    }
    inn_[t] = obs[(size_t)b*32 + t] - (acc + Hb[t]);
  }
  __syncthreads();

  // ---------------- HP = Hw @ pred_cov -> sT rows [0,32) (overwrites FP) ----------------
  {
    const int hr = t >> 4, hc0 = (t & 15)*4;   // 1x4 tile, 32x16 grid
    f32x4 acc = {0.0f,0.0f,0.0f,0.0f};
    for (int k = 0; k < 64; k += 4) {
      f32x4 a  = *(const f32x4*)&sHw[hr*LDF + k];
      f32x4 b0 = *(const f32x4*)&sP[(k  )*LDF + hc0];
      f32x4 b1v = *(const f32x4*)&sP[(k+1)*LDF + hc0];
      f32x4 b2v = *(const f32x4*)&sP[(k+2)*LDF + hc0];
      f32x4 b3v = *(const f32x4*)&sP[(k+3)*LDF + hc0];
      acc += a[0]*b0 + a[1]*b1v + a[2]*b2v + a[3]*b3v;
    }
    *(f32x4*)&sT[hr*LDF + hc0] = acc;
  }
  __syncthreads();

  // ---------------- S = HP @ Hw^T + Rn -> sS ----------------
  if (t < 256) {
    const int so = t >> 3, sp0 = (t & 7)*4;
    f32x4 accv = {0.0f,0.0f,0.0f,0.0f};
    for (int k = 0; k < 64; k += 4) {
      f32x4 av = *(const f32x4*)&sT[so*LDF + k];
      #pragma unroll
      for (int c = 0; c < 4; c++) {
        f32x4 bv = *(const f32x4*)&sHw[(sp0+c)*LDF + k];
        accv[c] += av[0]*bv[0] + av[1]*bv[1] + av[2]*bv[2] + av[3]*bv[3];
      }
    }
    #pragma unroll
    for (int c = 0; c < 4; c++) {
      int p = sp0 + c;
      float rn = sonf[so*4+0]*sonf[p*4+0] + sonf[so*4+1]*sonf[p*4+1] + sonf[so*4+2]*sonf[p*4+2];
      if (so == p) rn += sod[so];
      sS[so*SST + p] = accv[c] + rn;
    }
  }
  __syncthreads();

  // ---------------- Cholesky: wave 0, in-register, shfl broadcasts, NO barriers ----------
  if (t < 64) {
    const int lane = t;
    const int li = (lane < 32) ? lane : 0;
    float r[32];
    #pragma unroll
    for (int j = 0; j < 32; j++) r[j] = sS[li*SST + j];
    float my_sd = 1.0f;
    #pragma unroll
    for (int k = 0; k < 32; k++) {
      float dk = __shfl(r[k], k);
      float sd = sqrtf(dk);
      float lik = r[k] * (1.0f/sd);
      if (lane == k) my_sd = sd;
      r[k] = lik;
      #pragma unroll
      for (int j = k+1; j < 32; j++) {
        float ljk = __shfl(lik, j);
        if (lane >= j) r[j] -= lik * ljk;
      }
    }
    if (lane < 32) {
      #pragma unroll
      for (int j = 0; j < 32; j++) sS[lane*SST + j] = r[j];  // junk above diag, never read
      rdiag_[lane] = 1.0f / my_sd;
      redA[lane]   = logf(my_sd);
    }
  }
  __syncthreads();

  // ---------------- X = L^{-1} HP (wave 0: 64 cols) ; y = L^{-1} inn (wave 1) ----------
  if (t < 128) {
    float x[32];
    if (t < 64) {
      #pragma unroll
      for (int i = 0; i < 32; i++) x[i] = sT[i*LDF + t];
    } else {
      #pragma unroll
      for (int i = 0; i < 32; i++) x[i] = inn_[i];
    }
    #pragma unroll
    for (int m = 0; m < 32; m++) {
      x[m] *= rdiag_[m];
      #pragma unroll
      for (int i = m+1; i < 32; i++) x[i] -= sS[i*SST + m] * x[m];
    }
    if (t < 64) {
      #pragma unroll
      for (int i = 0; i < 32; i++) sT[XOFF + i*LDF + t] = x[i];
    } else if (t == 64) {
      float q = 0.0f;
      #pragma unroll
      for (int i = 0; i < 32; i++) { y_[i] = x[i]; q += x[i]*x[i]; }
      qd_ = q;
    }
  }
  __syncthreads();

  // ---------------- post_cov = pred_cov - X^T X -> global (non-temporal) ----------------
  {
    f32x4 acc0 = {0.0f,0.0f,0.0f,0.0f};
    f32x4 acc1 = {0.0f,0.0f,0.0f,0.0f};
    for (int o = 0; o < 32; o++) {
      f32x2 xa = *(const f32x2*)&sT[XOFF + o*LDF + i0];
      f32x4 xb = *(const f32x4*)&sT[XOFF + o*LDF + j0];
      acc0 += xa[0]*xb;
      acc1 += xa[1]*xb;
    }
    #pragma unroll
    for (int r = 0; r < 2; r++) {
      int i = i0 + r;
      f32x4 pv = *(const f32x4*)&sP[i*LDF + j0];
      f32x4 st = pv - ((r == 0) ? acc0 : acc1);
      __builtin_nontemporal_store(st, (f32x4*)&out_pc[(size_t)b*4096 + i*64 + j0]);
    }
  }
  // post_mean = pred_mean + X^T y
  if (t < 64) {
    float acc = pm_[t];
    #pragma unroll
    for (int i = 0; i < 32; i++) acc += sT[XOFF + i*LDF + t] * y_[i];
    __builtin_nontemporal_store(acc, &out_pm[(size_t)b*64 + t]);
  }
  // log-likelihood
  if (t == 0) {
    float ld = 0.0f;
    for (int k = 0; k < 32; k++) ld += redA[k];
    out_ll[b] = -0.5f*(2.0f*ld + qd_ + 32.0f*LOG2PI);
  }
}

extern "C" void kernel_launch(void* const* d_in, const int* in_sizes, int n_in,
                              void* d_out, int out_size, void* d_ws, size_t ws_size,
                              hipStream_t stream) {
  const float* state_mean = (const float*)d_in[0];
  const float* state_cov  = (const float*)d_in[1];
  const float* obs        = (const float*)d_in[2];
  const float* w1         = (const float*)d_in[3];
  const float* b1         = (const float*)d_in[4];
  const float* w2         = (const float*)d_in[5];
  const float* b2         = (const float*)d_in[6];
  const float* basis      = (const float*)d_in[7];
  const float* pnf        = (const float*)d_in[8];
  const float* pnd        = (const float*)d_in[9];
  const float* onf        = (const float*)d_in[10];
  const float* ond        = (const float*)d_in[11];
  const float* Hw         = (const float*)d_in[12];
  const float* Hb         = (const float*)d_in[13];

  const int Bn = in_sizes[0] / 64;
  float* out = (float*)d_out;
  float* out_pm = out;
  float* out_pc = out + (size_t)Bn*64;
  float* out_ll = out + (size_t)Bn*64 + (size_t)Bn*4096;

  hipLaunchKernelGGL(rkn_kernel, dim3(Bn), dim3(512), 0, stream,
                     state_mean, state_cov, obs, w1, b1, w2, b2, basis,
                     pnf, pnd, onf, ond, Hw, Hb, out_pm, out_pc, out_ll);
}

// Round 6
// 2448.334 us; speedup vs baseline: 1.6157x; 1.5477x over previous
//
#include <hip/hip_runtime.h>
#include <math.h>

// Problem constants (match reference)
#define NB   8192
#define DD   64
#define OO   32
#define KK   15
#define HID  60

#define LDF  68      // row stride (words) for 64-wide LDS tiles
#define LDT  72      // row stride for FP scratch tile
#define SST  36      // row stride for 32x32 matrices
#define XOFF (32*LDF)  // X = L^{-1} HP lives in sT after HP rows

#define LOG2PI 1.8378770664093453f

// clang ext vectors: stay in registers, support [] with constant index,
// scalar broadcast arithmetic, and nontemporal builtins. NEVER take their address.
typedef float f32x4 __attribute__((ext_vector_type(4)));
typedef float f32x2 __attribute__((ext_vector_type(2)));

// NOTE: single-arg launch_bounds — do NOT clamp waves/EU. LDS (70 KB) already
// limits occupancy to 2 blocks/CU (4 waves/SIMD); letting the allocator use
// up to 256 VGPRs costs nothing and (theory) eliminates scratch spills that
// generated ~2.9 KB/thread of HBM traffic (R2-R5 post-mortems).
__global__ __launch_bounds__(512)
void rkn_kernel(const float* __restrict__ state_mean,
                const float* __restrict__ state_cov,
                const float* __restrict__ obs,
                const float* __restrict__ w1,
                const float* __restrict__ b1,
                const float* __restrict__ w2,
                const float* __restrict__ b2,
                const float* __restrict__ basis,
                const float* __restrict__ pnf,
                const float* __restrict__ pnd,
                const float* __restrict__ onf,
                const float* __restrict__ ond,
                const float* __restrict__ Hw,
                const float* __restrict__ Hb,
                float* __restrict__ out_pm,
                float* __restrict__ out_pc,
                float* __restrict__ out_ll)
{
  __shared__ __align__(16) float sF [64*LDF];   // F
  __shared__ __align__(16) float sP [64*LDF];   // state_cov -> pred_cov
  __shared__ __align__(16) float sT [64*LDT];   // FP ; then HP rows [0,2176) + X [2176,4352)
  __shared__ __align__(16) float sHw[32*LDF];   // Hw staged
  __shared__ __align__(16) float sS [32*SST];   // S -> L
  __shared__ __align__(16) float sm_[64];
  __shared__ __align__(16) float pm_[64];
  __shared__ __align__(16) float h_ [64];
  __shared__ __align__(16) float inn_[32];
  __shared__ __align__(16) float y_ [32];
  __shared__ float wts_[16];
  __shared__ float redA[32];    // log(diag L)
  __shared__ float rdiag_[32];  // 1/diag(L)
  __shared__ float qd_;         // quad = y.y
  __shared__ __align__(16) float spnf[64*4];
  __shared__ float spd[64];
  __shared__ __align__(16) float sonf[32*4];
  __shared__ float sod[32];

  const int t = threadIdx.x;
  const int b = blockIdx.x;

  // ---------------- stage globals ----------------
  {
    const f32x4* cov4 = (const f32x4*)(state_cov + (size_t)b * 4096);
    #pragma unroll
    for (int r = 0; r < 2; r++) {
      int idx = t + 512*r;
      int row = idx >> 4, c4 = idx & 15;
      *(f32x4*)&sP[row*LDF + c4*4] = cov4[idx];
    }
    const f32x4* hw4 = (const f32x4*)Hw;
    {
      int row = t >> 4, c4 = t & 15;
      *(f32x4*)&sHw[row*LDF + c4*4] = hw4[t];
    }
    if (t < 64) {
      sm_[t] = state_mean[(size_t)b*64 + t];
      spnf[t*4+0] = pnf[t*3+0];
      spnf[t*4+1] = pnf[t*3+1];
      spnf[t*4+2] = pnf[t*3+2];
      spnf[t*4+3] = 0.0f;
      spd[t] = expf(pnd[t]);
    }
    if (t < 32) {
      sonf[t*4+0] = onf[t*3+0];
      sonf[t*4+1] = onf[t*3+1];
      sonf[t*4+2] = onf[t*3+2];
      sonf[t*4+3] = 0.0f;
      sod[t] = expf(ond[t]);
    }
  }
  __syncthreads();

  // ---------------- MLP: h = elu(W1 @ sm + b1) ----------------
  if (t < HID) {
    const f32x4* w1r = (const f32x4*)(w1 + t*64);
    float acc = 0.0f;
    #pragma unroll
    for (int m = 0; m < 16; m++) {
      f32x4 wv = w1r[m];
      f32x4 sv = *(const f32x4*)&sm_[4*m];
      acc += wv[0]*sv[0] + wv[1]*sv[1] + wv[2]*sv[2] + wv[3]*sv[3];
    }
    acc += b1[t];
    h_[t] = (acc > 0.0f) ? acc : expm1f(acc);
  }
  __syncthreads();

  // logits = W2 @ h + b2
  if (t < KK) {
    const float* w2r = w2 + t*60;
    float acc = 0.0f;
    for (int m = 0; m < 60; m++) acc += w2r[m]*h_[m];
    wts_[t] = acc + b2[t];
  }
  __syncthreads();

  // softmax over 15 (serial, tiny)
  if (t == 0) {
    float mx = wts_[0];
    for (int k = 1; k < KK; k++) mx = fmaxf(mx, wts_[k]);
    float s = 0.0f;
    for (int k = 0; k < KK; k++) { float e = expf(wts_[k]-mx); wts_[k] = e; s += e; }
    float inv = 1.0f/s;
    for (int k = 0; k < KK; k++) wts_[k] *= inv;
  }
  __syncthreads();

  // ---------------- F = sum_k w_k * basis_k (wts_ read via LDS broadcast, no array) ---
  {
    const f32x4* bas4 = (const f32x4*)basis;
    #pragma unroll
    for (int r = 0; r < 2; r++) {
      int idx = t + 512*r;
      f32x4 acc = {0.0f, 0.0f, 0.0f, 0.0f};
      #pragma unroll
      for (int k = 0; k < KK; k++) {
        f32x4 bv = bas4[k*1024 + idx];
        acc += wts_[k]*bv;
      }
      int row = idx >> 4, c4 = idx & 15;
      *(f32x4*)&sF[row*LDF + c4*4] = acc;
    }
  }
  __syncthreads();

  const int tr = t >> 4, tc = t & 15;   // 32 x 16 thread grid
  const int i0 = tr*2, j0 = tc*4;       // 2x4 output tile

  // ---------------- FP = F @ P  -> sT ; pred_mean = F @ sm ----------------
  {
    f32x4 acc0 = {0.0f,0.0f,0.0f,0.0f};
    f32x4 acc1 = {0.0f,0.0f,0.0f,0.0f};
    for (int k = 0; k < 64; k += 4) {
      f32x4 a0 = *(const f32x4*)&sF[(i0  )*LDF + k];
      f32x4 a1 = *(const f32x4*)&sF[(i0+1)*LDF + k];
      f32x4 b0 = *(const f32x4*)&sP[(k  )*LDF + j0];
      f32x4 b1v = *(const f32x4*)&sP[(k+1)*LDF + j0];
      f32x4 b2v = *(const f32x4*)&sP[(k+2)*LDF + j0];
      f32x4 b3v = *(const f32x4*)&sP[(k+3)*LDF + j0];
      acc0 += a0[0]*b0 + a0[1]*b1v + a0[2]*b2v + a0[3]*b3v;
      acc1 += a1[0]*b0 + a1[1]*b1v + a1[2]*b2v + a1[3]*b3v;
    }
    *(f32x4*)&sT[(i0  )*LDT + j0] = acc0;
    *(f32x4*)&sT[(i0+1)*LDT + j0] = acc1;
  }
  if (t < 64) {
    float acc = 0.0f;
    #pragma unroll
    for (int m = 0; m < 16; m++) {
      f32x4 fv = *(const f32x4*)&sF[t*LDF + 4*m];
      f32x4 sv = *(const f32x4*)&sm_[4*m];
      acc += fv[0]*sv[0] + fv[1]*sv[1] + fv[2]*sv[2] + fv[3]*sv[3];
    }
    pm_[t] = acc;
  }
  __syncthreads();

  // ---------------- pred_cov = FP @ F^T + Q -> sP ; innovation ----------------
  {
    f32x4 acc0 = {0.0f,0.0f,0.0f,0.0f};
    f32x4 acc1 = {0.0f,0.0f,0.0f,0.0f};
    for (int k = 0; k < 64; k += 4) {
      f32x4 a0 = *(const f32x4*)&sT[(i0  )*LDT + k];
      f32x4 a1 = *(const f32x4*)&sT[(i0+1)*LDT + k];
      #pragma unroll
      for (int c = 0; c < 4; c++) {
        f32x4 bv = *(const f32x4*)&sF[(j0+c)*LDF + k];
        acc0[c] += a0[0]*bv[0] + a0[1]*bv[1] + a0[2]*bv[2] + a0[3]*bv[3];
        acc1[c] += a1[0]*bv[0] + a1[1]*bv[1] + a1[2]*bv[2] + a1[3]*bv[3];
      }
    }
    #pragma unroll
    for (int r = 0; r < 2; r++) {
      int i = i0 + r;
      f32x4 st = (r == 0) ? acc0 : acc1;
      #pragma unroll
      for (int c = 0; c < 4; c++) {
        int j = j0 + c;
        float q = spnf[i*4+0]*spnf[j*4+0] + spnf[i*4+1]*spnf[j*4+1] + spnf[i*4+2]*spnf[j*4+2];
        if (i == j) q += spd[i];
        st[c] += q;
      }
      *(f32x4*)&sP[i*LDF + j0] = st;
    }
  }
  if (t < 32) {
    float acc = 0.0f;
    #pragma unroll
    for (int m = 0; m < 16; m++) {
      f32x4 hv = *(const f32x4*)&sHw[t*LDF + 4*m];
      f32x4 pv = *(const f32x4*)&pm_[4*m];
      acc += hv[0]*pv[0] + hv[1]*pv[1] + hv[2]*pv[2] + hv[3]*pv[3];
    }
    inn_[t] = obs[(size_t)b*32 + t] - (acc + Hb[t]);
  }
  __syncthreads();

  // ---------------- HP = Hw @ pred_cov -> sT rows [0,32) (overwrites FP) ----------------
  {
    const int hr = t >> 4, hc0 = (t & 15)*4;   // 1x4 tile, 32x16 grid
    f32x4 acc = {0.0f,0.0f,0.0f,0.0f};
    for (int k = 0; k < 64; k += 4) {
      f32x4 a  = *(const f32x4*)&sHw[hr*LDF + k];
      f32x4 b0 = *(const f32x4*)&sP[(k  )*LDF + hc0];
      f32x4 b1v = *(const f32x4*)&sP[(k+1)*LDF + hc0];
      f32x4 b2v = *(const f32x4*)&sP[(k+2)*LDF + hc0];
      f32x4 b3v = *(const f32x4*)&sP[(k+3)*LDF + hc0];
      acc += a[0]*b0 + a[1]*b1v + a[2]*b2v + a[3]*b3v;
    }
    *(f32x4*)&sT[hr*LDF + hc0] = acc;
  }
  __syncthreads();

  // ---------------- S = HP @ Hw^T + Rn -> sS ----------------
  if (t < 256) {
    const int so = t >> 3, sp0 = (t & 7)*4;
    f32x4 accv = {0.0f,0.0f,0.0f,0.0f};
    for (int k = 0; k < 64; k += 4) {
      f32x4 av = *(const f32x4*)&sT[so*LDF + k];
      #pragma unroll
      for (int c = 0; c < 4; c++) {
        f32x4 bv = *(const f32x4*)&sHw[(sp0+c)*LDF + k];
        accv[c] += av[0]*bv[0] + av[1]*bv[1] + av[2]*bv[2] + av[3]*bv[3];
      }
    }
    #pragma unroll
    for (int c = 0; c < 4; c++) {
      int p = sp0 + c;
      float rn = sonf[so*4+0]*sonf[p*4+0] + sonf[so*4+1]*sonf[p*4+1] + sonf[so*4+2]*sonf[p*4+2];
      if (so == p) rn += sod[so];
      sS[so*SST + p] = accv[c] + rn;
    }
  }
  __syncthreads();

  // ---------------- Cholesky: wave 0, in-register, shfl broadcasts, NO barriers ----------
  if (t < 64) {
    const int lane = t;
    const int li = (lane < 32) ? lane : 0;
    float r[32];
    #pragma unroll
    for (int j = 0; j < 32; j++) r[j] = sS[li*SST + j];
    float my_sd = 1.0f;
    #pragma unroll
    for (int k = 0; k < 32; k++) {
      float dk = __shfl(r[k], k);
      float sd = sqrtf(dk);
      float lik = r[k] * (1.0f/sd);
      if (lane == k) my_sd = sd;
      r[k] = lik;
      #pragma unroll
      for (int j = k+1; j < 32; j++) {
        float ljk = __shfl(lik, j);
        if (lane >= j) r[j] -= lik * ljk;
      }
    }
    if (lane < 32) {
      #pragma unroll
      for (int j = 0; j < 32; j++) sS[lane*SST + j] = r[j];  // junk above diag, never read
      rdiag_[lane] = 1.0f / my_sd;
      redA[lane]   = logf(my_sd);
    }
  }
  __syncthreads();

  // ---------------- X = L^{-1} HP (wave 0: 64 cols) ; y = L^{-1} inn (wave 1) ----------
  if (t < 128) {
    float x[32];
    if (t < 64) {
      #pragma unroll
      for (int i = 0; i < 32; i++) x[i] = sT[i*LDF + t];
    } else {
      #pragma unroll
      for (int i = 0; i < 32; i++) x[i] = inn_[i];
    }
    #pragma unroll
    for (int m = 0; m < 32; m++) {
      x[m] *= rdiag_[m];
      #pragma unroll
      for (int i = m+1; i < 32; i++) x[i] -= sS[i*SST + m] * x[m];
    }
    if (t < 64) {
      #pragma unroll
      for (int i = 0; i < 32; i++) sT[XOFF + i*LDF + t] = x[i];
    } else if (t == 64) {
      float q = 0.0f;
      #pragma unroll
      for (int i = 0; i < 32; i++) { y_[i] = x[i]; q += x[i]*x[i]; }
      qd_ = q;
    }
  }
  __syncthreads();

  // ---------------- post_cov = pred_cov - X^T X -> global (non-temporal) ----------------
  {
    f32x4 acc0 = {0.0f,0.0f,0.0f,0.0f};
    f32x4 acc1 = {0.0f,0.0f,0.0f,0.0f};
    for (int o = 0; o < 32; o++) {
      f32x2 xa = *(const f32x2*)&sT[XOFF + o*LDF + i0];
      f32x4 xb = *(const f32x4*)&sT[XOFF + o*LDF + j0];
      acc0 += xa[0]*xb;
      acc1 += xa[1]*xb;
    }
    #pragma unroll
    for (int r = 0; r < 2; r++) {
      int i = i0 + r;
      f32x4 pv = *(const f32x4*)&sP[i*LDF + j0];
      f32x4 st = pv - ((r == 0) ? acc0 : acc1);
      __builtin_nontemporal_store(st, (f32x4*)&out_pc[(size_t)b*4096 + i*64 + j0]);
    }
  }
  // post_mean = pred_mean + X^T y
  if (t < 64) {
    float acc = pm_[t];
    #pragma unroll
    for (int i = 0; i < 32; i++) acc += sT[XOFF + i*LDF + t] * y_[i];
    __builtin_nontemporal_store(acc, &out_pm[(size_t)b*64 + t]);
  }
  // log-likelihood
  if (t == 0) {
    float ld = 0.0f;
    for (int k = 0; k < 32; k++) ld += redA[k];
    out_ll[b] = -0.5f*(2.0f*ld + qd_ + 32.0f*LOG2PI);
  }
}

extern "C" void kernel_launch(void* const* d_in, const int* in_sizes, int n_in,
                              void* d_out, int out_size, void* d_ws, size_t ws_size,
                              hipStream_t stream) {
  const float* state_mean = (const float*)d_in[0];
  const float* state_cov  = (const float*)d_in[1];
  const float* obs        = (const float*)d_in[2];
  const float* w1         = (const float*)d_in[3];
  const float* b1         = (const float*)d_in[4];
  const float* w2         = (const float*)d_in[5];
  const float* b2         = (const float*)d_in[6];
  const float* basis      = (const float*)d_in[7];
  const float* pnf        = (const float*)d_in[8];
  const float* pnd        = (const float*)d_in[9];
  const float* onf        = (const float*)d_in[10];
  const float* ond        = (const float*)d_in[11];
  const float* Hw         = (const float*)d_in[12];
  const float* Hb         = (const float*)d_in[13];

  const int Bn = in_sizes[0] / 64;
  float* out = (float*)d_out;
  float* out_pm = out;
  float* out_pc = out + (size_t)Bn*64;
  float* out_ll = out + (size_t)Bn*64 + (size_t)Bn*4096;

  hipLaunchKernelGGL(rkn_kernel, dim3(Bn), dim3(512), 0, stream,
                     state_mean, state_cov, obs, w1, b1, w2, b2, basis,
                     pnf, pnd, onf, ond, Hw, Hb, out_pm, out_pc, out_ll);
}